// Round 1
// baseline (460.697 us; speedup 1.0000x reference)
//
#include <hip/hip_runtime.h>

// MoE EP-combine: out[idx[r]] += gates[r] * expert[r]   (fp32)
// Strategy: invert scatter -> gather. Tiny CSR-lite build (counts + fixed-width
// slot lists) then one block per output token reads its contributor rows,
// weights, sums, writes once. Output fully written => no pre-zero of d_out.

static constexpr int NT   = 256;  // threads per block
static constexpr int MAXK = 32;   // max contributors per token (Poisson(2) max ~10)

// ws layout: [0..3] int64-flag | [256 ...] counts[num_tokens] | slots[num_tokens*MAXK]

// Detect whether the index buffer is int64 (odd int32 words all zero) or int32.
__global__ void detect_kernel(const int* __restrict__ idx32, int* __restrict__ flag) {
    int all0 = 1;
#pragma unroll
    for (int i = 1; i < 16; i += 2) all0 &= (idx32[i] == 0);
    *flag = all0;  // 1 => int64 layout, 0 => int32 layout
}

__global__ void fill_kernel(const int* __restrict__ idx32,
                            const long long* __restrict__ idx64,
                            const int* __restrict__ flag,
                            int* __restrict__ counts,
                            int* __restrict__ slots,
                            int num_sel, int num_tokens) {
    int r = blockIdx.x * blockDim.x + threadIdx.x;
    if (r >= num_sel) return;
    int t = (*flag) ? (int)idx64[r] : idx32[r];
    if (t < 0 || t >= num_tokens) return;  // safety net
    int j = atomicAdd(&counts[t], 1);
    if (j < MAXK) slots[t * MAXK + j] = r;
}

// Specialized for d_model == 2048: 256 threads * 2 float4 each.
__global__ __launch_bounds__(NT) void combine2048_kernel(
    const float* __restrict__ expert,
    const float* __restrict__ gates,
    const int* __restrict__ counts,
    const int* __restrict__ slots,
    float* __restrict__ out) {
    const int t   = blockIdx.x;
    const int tid = threadIdx.x;
    int c = counts[t];
    if (c > MAXK) c = MAXK;
    const int* sl = slots + t * MAXK;

    float4 a0 = make_float4(0.f, 0.f, 0.f, 0.f);
    float4 a1 = a0;
    for (int j = 0; j < c; ++j) {
        int   r = sl[j];                 // wave-uniform
        float g = gates[r];              // wave-uniform, L1 broadcast
        const float4* row = (const float4*)(expert + (size_t)r * 2048);
        float4 e0 = row[tid];
        float4 e1 = row[tid + NT];
        a0.x = fmaf(g, e0.x, a0.x); a0.y = fmaf(g, e0.y, a0.y);
        a0.z = fmaf(g, e0.z, a0.z); a0.w = fmaf(g, e0.w, a0.w);
        a1.x = fmaf(g, e1.x, a1.x); a1.y = fmaf(g, e1.y, a1.y);
        a1.z = fmaf(g, e1.z, a1.z); a1.w = fmaf(g, e1.w, a1.w);
    }
    float4* o = (float4*)(out + (size_t)t * 2048);
    o[tid]      = a0;
    o[tid + NT] = a1;
}

// Fallback: plain atomic scatter (generic d_model, or ws too small).
__global__ void scatter_atomic_kernel(const float* __restrict__ expert,
                                      const float* __restrict__ gates,
                                      const int* __restrict__ idx32,
                                      const long long* __restrict__ idx64,
                                      const int* __restrict__ flag,  // may be null => int32
                                      float* __restrict__ out,
                                      int d_model) {
    int r = blockIdx.x;
    int is64 = flag ? *flag : 0;
    int t = is64 ? (int)idx64[r] : idx32[r];
    float g = gates[r];
    const float* row  = expert + (size_t)r * d_model;
    float*       orow = out    + (size_t)t * d_model;
    for (int v = threadIdx.x; v < d_model; v += blockDim.x)
        atomicAdd(&orow[v], g * row[v]);
}

extern "C" void kernel_launch(void* const* d_in, const int* in_sizes, int n_in,
                              void* d_out, int out_size, void* d_ws, size_t ws_size,
                              hipStream_t stream) {
    const float*      expert = (const float*)d_in[1];
    const float*      gates  = (const float*)d_in[2];
    const int*        idx32  = (const int*)d_in[3];
    const long long*  idx64  = (const long long*)d_in[3];
    float*            out    = (float*)d_out;

    const int num_sel = in_sizes[2];
    const int d_model = (int)((long long)in_sizes[1] / num_sel);
    const int num_tokens = (int)((long long)out_size / d_model);

    int*  flag   = (int*)d_ws;
    int*  counts = (int*)((char*)d_ws + 256);
    int*  slots  = (int*)((char*)d_ws + 256 + (size_t)num_tokens * 4);
    const size_t need = 256 + (size_t)num_tokens * 4 + (size_t)num_tokens * MAXK * 4;

    if (d_model == 2048 && ws_size >= need) {
        // zero flag + counts (re-poisoned to 0xAA before every timed launch)
        hipMemsetAsync(d_ws, 0, 256 + (size_t)num_tokens * 4, stream);
        detect_kernel<<<1, 1, 0, stream>>>(idx32, flag);
        fill_kernel<<<(num_sel + NT - 1) / NT, NT, 0, stream>>>(
            idx32, idx64, flag, counts, slots, num_sel, num_tokens);
        combine2048_kernel<<<num_tokens, NT, 0, stream>>>(expert, gates, counts, slots, out);
    } else {
        hipMemsetAsync(d_out, 0, (size_t)out_size * sizeof(float), stream);
        int* fl = nullptr;
        if (ws_size >= 4) {
            fl = flag;
            detect_kernel<<<1, 1, 0, stream>>>(idx32, fl);
        }
        scatter_atomic_kernel<<<num_sel, NT, 0, stream>>>(
            expert, gates, idx32, idx64, fl, out, d_model);
    }
}

// Round 3
// 438.319 us; speedup vs baseline: 1.0511x; 1.0511x over previous
//
#include <hip/hip_runtime.h>

// MoE EP-combine: out[idx[r]] += gates[r] * expert[r]   (fp32)
// Gather formulation: CSR-lite build (counts + fixed-width slot lists), then
// 2 blocks per output token gather contributor half-rows, weight, sum, write
// once (no pre-zero of d_out needed: every output element written).

static constexpr int NT   = 256;  // threads per block
static constexpr int MAXK = 32;   // max contributors per token (Poisson(2) max ~10)

typedef float fvec4 __attribute__((ext_vector_type(4)));  // clang vector: OK for nontemporal builtins

// ws layout: [0 ..) counts[num_tokens] | slots[num_tokens*MAXK]

__global__ void fill_kernel(const int* __restrict__ idx32,
                            const long long* __restrict__ idx64,
                            int* __restrict__ counts,
                            int* __restrict__ slots,
                            int num_sel, int num_tokens) {
    int r = blockIdx.x * blockDim.x + threadIdx.x;
    if (r >= num_sel) return;
    // Inline int64-layout detection: if the buffer is int64 (little-endian),
    // the high 32-bit words of the first 16 values are all zero (indices are
    // small non-negative). For int32 data those words are 16 independent
    // token indices -- all-zero with probability ~16384^-16. Wave-uniform
    // reads of the same 128 B -> L1 broadcast, ~free.
    int is64 = 1;
#pragma unroll
    for (int i = 1; i < 32; i += 2) is64 &= (idx32[i] == 0);
    int t = is64 ? (int)idx64[r] : idx32[r];
    if ((unsigned)t >= (unsigned)num_tokens) return;  // safety net
    int j = atomicAdd(&counts[t], 1);
    if (j < MAXK) slots[t * MAXK + j] = r;
}

// Specialized for d_model == 2048: 2 blocks per token, 1 float4 per thread.
__global__ __launch_bounds__(NT) void combine2048_kernel(
    const float* __restrict__ expert,
    const float* __restrict__ gates,
    const int* __restrict__ counts,
    const int* __restrict__ slots,
    float* __restrict__ out) {
    const int b    = blockIdx.x;
    const int t    = b >> 1;                       // token
    const int col4 = ((b & 1) * NT + threadIdx.x); // float4 index in [0,512)
    int c = counts[t];
    if (c > MAXK) c = MAXK;
    const int* sl = slots + t * MAXK;

    fvec4 acc = (fvec4)(0.f);
    for (int j = 0; j < c; ++j) {
        int   r = sl[j];                 // wave-uniform
        float g = gates[r];              // wave-uniform
        const fvec4* row = (const fvec4*)(expert + (size_t)r * 2048);
        fvec4 e = __builtin_nontemporal_load(row + col4);  // streamed once: nt
        acc.x = fmaf(g, e.x, acc.x);
        acc.y = fmaf(g, e.y, acc.y);
        acc.z = fmaf(g, e.z, acc.z);
        acc.w = fmaf(g, e.w, acc.w);
    }
    fvec4* o = (fvec4*)(out + (size_t)t * 2048);
    __builtin_nontemporal_store(acc, o + col4);  // write-only: nt
}

// Fallback: plain atomic scatter (generic d_model, or ws too small).
__global__ void scatter_atomic_kernel(const float* __restrict__ expert,
                                      const float* __restrict__ gates,
                                      const int* __restrict__ idx32,
                                      const long long* __restrict__ idx64,
                                      float* __restrict__ out,
                                      int d_model, int num_tokens) {
    int r = blockIdx.x;
    int is64 = 1;
#pragma unroll
    for (int i = 1; i < 32; i += 2) is64 &= (idx32[i] == 0);
    int t = is64 ? (int)idx64[r] : idx32[r];
    if ((unsigned)t >= (unsigned)num_tokens) return;
    float g = gates[r];
    const float* row  = expert + (size_t)r * d_model;
    float*       orow = out    + (size_t)t * d_model;
    for (int v = threadIdx.x; v < d_model; v += blockDim.x)
        atomicAdd(&orow[v], g * row[v]);
}

extern "C" void kernel_launch(void* const* d_in, const int* in_sizes, int n_in,
                              void* d_out, int out_size, void* d_ws, size_t ws_size,
                              hipStream_t stream) {
    const float*      expert = (const float*)d_in[1];
    const float*      gates  = (const float*)d_in[2];
    const int*        idx32  = (const int*)d_in[3];
    const long long*  idx64  = (const long long*)d_in[3];
    float*            out    = (float*)d_out;

    const int num_sel    = in_sizes[2];
    const int d_model    = (int)((long long)in_sizes[1] / num_sel);
    const int num_tokens = (int)((long long)out_size / d_model);

    int*  counts = (int*)d_ws;
    int*  slots  = (int*)((char*)d_ws + (size_t)num_tokens * 4);
    const size_t need = (size_t)num_tokens * 4 + (size_t)num_tokens * MAXK * 4;

    if (d_model == 2048 && ws_size >= need) {
        (void)hipMemsetAsync(counts, 0, (size_t)num_tokens * 4, stream);  // ws re-poisoned 0xAA
        fill_kernel<<<(num_sel + NT - 1) / NT, NT, 0, stream>>>(
            idx32, idx64, counts, slots, num_sel, num_tokens);
        combine2048_kernel<<<num_tokens * 2, NT, 0, stream>>>(expert, gates, counts, slots, out);
    } else {
        (void)hipMemsetAsync(d_out, 0, (size_t)out_size * sizeof(float), stream);
        scatter_atomic_kernel<<<num_sel, NT, 0, stream>>>(
            expert, gates, idx32, idx64, out, d_model, num_tokens);
    }
}